// Round 1
// baseline (18.945 us; speedup 1.0000x reference)
//
#include <hip/hip_runtime.h>
#include <hip/hip_bf16.h>

// TCN: only the last timestep of conv2 output feeds the FC layer.
// h2[:, :, S-1] needs h1 at S-3..S-1, which needs x at S-5..S-1.
// Total work ~2.4 MFLOP — latency/launch bound, not roofline bound.

#define S_LEN   16384
#define C_IN    64
#define HID     128
#define C_OUT   64
#define KW      3

__global__ __launch_bounds__(128)
void tcn_tail_kernel(const float* __restrict__ x,
                     const float* __restrict__ w1, const float* __restrict__ b1,
                     const float* __restrict__ w2, const float* __restrict__ b2,
                     const float* __restrict__ fw, const float* __restrict__ fb,
                     float* __restrict__ out)
{
    const int b   = blockIdx.x;
    const int tid = threadIdx.x;

    __shared__ float xs[5][C_IN];   // x timesteps S-5 .. S-1 (transposed view: xs[t][c])
    __shared__ float h1[3][HID];    // conv1 output at timesteps S-3 .. S-1
    __shared__ float h2[HID];       // conv2 output at timestep S-1

    // ---- stage x tail: 5*64 = 320 floats ----
    // x layout (B, S, C) row-major: x[b][s][c] -> b*S_LEN*C_IN + s*C_IN + c
    const float* xb = x + (size_t)b * S_LEN * C_IN + (size_t)(S_LEN - 5) * C_IN;
    for (int i = tid; i < 5 * C_IN; i += blockDim.x)
        xs[i / C_IN][i % C_IN] = xb[i];
    __syncthreads();

    // ---- conv1: thread tid = hidden channel h; compute timesteps S-3..S-1 ----
    // h1[b][h][s] = relu(b1[h] + sum_{c,j} x[b][s+j-2][c] * w1[h][c*3+j])
    // For t = 0..2 (s = S-3+t): input timestep index into xs is (t + j).
    {
        const int h = tid;
        const float* w1r = w1 + (size_t)h * (C_IN * KW);
        float a0 = b1[h], a1 = a0, a2 = a0;
        #pragma unroll 8
        for (int c = 0; c < C_IN; ++c) {
            const float wj0 = w1r[c * KW + 0];
            const float wj1 = w1r[c * KW + 1];
            const float wj2 = w1r[c * KW + 2];
            const float x0 = xs[0][c], x1 = xs[1][c], x2 = xs[2][c];
            const float x3 = xs[3][c], x4 = xs[4][c];
            a0 += wj0 * x0 + wj1 * x1 + wj2 * x2;
            a1 += wj0 * x1 + wj1 * x2 + wj2 * x3;
            a2 += wj0 * x2 + wj1 * x3 + wj2 * x4;
        }
        h1[0][h] = fmaxf(a0, 0.0f);
        h1[1][h] = fmaxf(a1, 0.0f);
        h1[2][h] = fmaxf(a2, 0.0f);
    }
    __syncthreads();

    // ---- conv2 at timestep S-1: needs h1 timesteps j=0..2 (S-3+j) ----
    // h2[h] = relu(b2[h] + sum_{c,j} h1[j][c] * w2[h][c*3+j])
    {
        const int h = tid;
        const float* w2r = w2 + (size_t)h * (HID * KW);
        float a = b2[h];
        #pragma unroll 8
        for (int c = 0; c < HID; ++c) {
            a += w2r[c * KW + 0] * h1[0][c]
               + w2r[c * KW + 1] * h1[1][c]
               + w2r[c * KW + 2] * h1[2][c];
        }
        h2[h] = fmaxf(a, 0.0f);
    }
    __syncthreads();

    // ---- fc: threads 0..63, out[b][o] = fb[o] + sum_c h2[c] * fw[o][c] ----
    if (tid < C_OUT) {
        const float* fwr = fw + (size_t)tid * HID;
        float a = fb[tid];
        #pragma unroll 8
        for (int c = 0; c < HID; ++c)
            a += fwr[c] * h2[c];
        out[(size_t)b * C_OUT + tid] = a;
    }
}

extern "C" void kernel_launch(void* const* d_in, const int* in_sizes, int n_in,
                              void* d_out, int out_size, void* d_ws, size_t ws_size,
                              hipStream_t stream) {
    const float* x  = (const float*)d_in[0];
    const float* w1 = (const float*)d_in[1];
    const float* b1 = (const float*)d_in[2];
    const float* w2 = (const float*)d_in[3];
    const float* b2 = (const float*)d_in[4];
    const float* fw = (const float*)d_in[5];
    const float* fb = (const float*)d_in[6];
    float* out = (float*)d_out;

    tcn_tail_kernel<<<16, 128, 0, stream>>>(x, w1, b1, w2, b2, fw, fb, out);
}

// Round 2
// 9.326 us; speedup vs baseline: 2.0313x; 2.0313x over previous
//
#include <hip/hip_runtime.h>
#include <hip/hip_bf16.h>

// TCN: only the last timestep survives. h2[:, :, S-1] needs h1 at S-3..S-1,
// which needs x at S-5..S-1. ~2.4 MFLOP total -> latency bound.
//
// This version: 512 threads/block (8 waves), 4 lanes per conv dot-product /
// 8 lanes per fc dot-product, interleaved float4 chunks so adjacent lanes
// read adjacent 16B (coalesced 64B lines from global, distinct LDS banks),
// shfl_xor reductions. One block per batch.

#define S_LEN   16384
#define C_IN    64
#define HID     128
#define C_OUT   64
#define KW      3

__global__ __launch_bounds__(512)
void tcn_tail_kernel(const float* __restrict__ x,
                     const float* __restrict__ w1, const float* __restrict__ b1,
                     const float* __restrict__ w2, const float* __restrict__ b2,
                     const float* __restrict__ fw, const float* __restrict__ fb,
                     float* __restrict__ out)
{
    const int b   = blockIdx.x;
    const int tid = threadIdx.x;

    __shared__ float xf[3][C_IN * KW];  // xf[t][c*3+j] = x[S-5 + t + j][c]
    __shared__ float h1f[HID * KW];     // h1f[h*3+t]   = relu(conv1_h at S-3+t)
    __shared__ float h2s[HID];          // conv2 output at S-1

    // ---- stage x tail (320 floats) directly into the 3 flat operand vectors ----
    // x layout (B, S, C): x[b][s][c] -> b*S*C + s*C + c
    const float* xb = x + (size_t)b * S_LEN * C_IN + (size_t)(S_LEN - 5) * C_IN;
    if (tid < 5 * C_IN) {
        const float v = xb[tid];
        const int s = tid >> 6;       // 0..4  (timestep S-5+s)
        const int c = tid & 63;
        #pragma unroll
        for (int t = 0; t < 3; ++t) {
            const int j = s - t;
            if (0 <= j && j < KW) xf[t][c * KW + j] = v;
        }
    }
    __syncthreads();

    // ---- conv1: 128 outputs x 3 timesteps; 4 lanes per output ----
    // h1f[h*3+t] = relu(b1[h] + dot(w1[h,:], xf[t,:]))   (length 192)
    {
        const int h = tid >> 2;       // 0..127
        const int q = tid & 3;        // lane-within-group
        const float4* wv = (const float4*)(w1 + (size_t)h * (C_IN * KW));
        float a0 = 0.f, a1 = 0.f, a2 = 0.f;
        #pragma unroll
        for (int m = 0; m < 12; ++m) {
            const int ch = m * 4 + q;           // interleaved float4 chunk
            const float4 w  = wv[ch];
            const float4 p0 = ((const float4*)xf[0])[ch];
            const float4 p1 = ((const float4*)xf[1])[ch];
            const float4 p2 = ((const float4*)xf[2])[ch];
            a0 += w.x * p0.x + w.y * p0.y + w.z * p0.z + w.w * p0.w;
            a1 += w.x * p1.x + w.y * p1.y + w.z * p1.z + w.w * p1.w;
            a2 += w.x * p2.x + w.y * p2.y + w.z * p2.z + w.w * p2.w;
        }
        a0 += __shfl_xor(a0, 1); a0 += __shfl_xor(a0, 2);
        a1 += __shfl_xor(a1, 1); a1 += __shfl_xor(a1, 2);
        a2 += __shfl_xor(a2, 1); a2 += __shfl_xor(a2, 2);
        if (q == 0) {
            const float bb = b1[h];
            h1f[h * KW + 0] = fmaxf(a0 + bb, 0.f);
            h1f[h * KW + 1] = fmaxf(a1 + bb, 0.f);
            h1f[h * KW + 2] = fmaxf(a2 + bb, 0.f);
        }
    }
    __syncthreads();

    // ---- conv2 at S-1: 128 outputs, dot length 384; 4 lanes per output ----
    // h2[h] = relu(b2[h] + dot(w2[h,:], h1f[:]))
    {
        const int h = tid >> 2;
        const int q = tid & 3;
        const float4* wv = (const float4*)(w2 + (size_t)h * (HID * KW));
        const float4* hv = (const float4*)h1f;
        float a0 = 0.f, a1 = 0.f, a2 = 0.f, a3 = 0.f;
        #pragma unroll
        for (int m = 0; m < 24; m += 4) {
            const int c0 = (m + 0) * 4 + q;
            const int c1 = (m + 1) * 4 + q;
            const int c2 = (m + 2) * 4 + q;
            const int c3 = (m + 3) * 4 + q;
            const float4 w0 = wv[c0], w1v = wv[c1], w2v = wv[c2], w3v = wv[c3];
            const float4 p0 = hv[c0], p1 = hv[c1], p2 = hv[c2], p3 = hv[c3];
            a0 += w0.x * p0.x + w0.y * p0.y + w0.z * p0.z + w0.w * p0.w;
            a1 += w1v.x * p1.x + w1v.y * p1.y + w1v.z * p1.z + w1v.w * p1.w;
            a2 += w2v.x * p2.x + w2v.y * p2.y + w2v.z * p2.z + w2v.w * p2.w;
            a3 += w3v.x * p3.x + w3v.y * p3.y + w3v.z * p3.z + w3v.w * p3.w;
        }
        float a = (a0 + a1) + (a2 + a3);
        a += __shfl_xor(a, 1); a += __shfl_xor(a, 2);
        if (q == 0) h2s[h] = fmaxf(a + b2[h], 0.f);
    }
    __syncthreads();

    // ---- fc: 64 outputs, dot length 128; 8 lanes per output ----
    {
        const int o = tid >> 3;       // 0..63
        const int r = tid & 7;
        const float4* wv = (const float4*)(fw + (size_t)o * HID);
        const float4* hv = (const float4*)h2s;
        float a = 0.f;
        #pragma unroll
        for (int m = 0; m < 4; ++m) {
            const int ch = m * 8 + r;
            const float4 w  = wv[ch];
            const float4 p  = hv[ch];
            a += w.x * p.x + w.y * p.y + w.z * p.z + w.w * p.w;
        }
        a += __shfl_xor(a, 1); a += __shfl_xor(a, 2); a += __shfl_xor(a, 4);
        if (r == 0) out[(size_t)b * C_OUT + o] = a + fb[o];
    }
}

extern "C" void kernel_launch(void* const* d_in, const int* in_sizes, int n_in,
                              void* d_out, int out_size, void* d_ws, size_t ws_size,
                              hipStream_t stream) {
    const float* x  = (const float*)d_in[0];
    const float* w1 = (const float*)d_in[1];
    const float* b1 = (const float*)d_in[2];
    const float* w2 = (const float*)d_in[3];
    const float* b2 = (const float*)d_in[4];
    const float* fw = (const float*)d_in[5];
    const float* fb = (const float*)d_in[6];
    float* out = (float*)d_out;

    tcn_tail_kernel<<<16, 512, 0, stream>>>(x, w1, b1, w2, b2, fw, fb, out);
}